// Round 4
// baseline (1390.990 us; speedup 1.0000x reference)
//
#include <hip/hip_runtime.h>
#include <stdint.h>

#define EPS 1e-5f
#define SLOPE 0.01f

typedef short bf16x8 __attribute__((ext_vector_type(8)));
typedef float f32x4 __attribute__((ext_vector_type(4)));

// round-to-nearest-even fp32 -> bf16
__device__ __forceinline__ uint16_t f2bf(float x) {
  union { float f; uint32_t u; } v; v.f = x;
  return (uint16_t)((v.u + 0x7fffu + ((v.u >> 16) & 1u)) >> 16);
}

// async global->LDS, 16B per lane; LDS dest = wave-uniform base + lane*16
__device__ __forceinline__ void g2lds16(const void* g, void* l) {
  __builtin_amdgcn_global_load_lds(
      (const __attribute__((address_space(1))) void*)g,
      (__attribute__((address_space(3))) void*)l, 16, 0, 0);
}

// counted vmem wait: allow n loads to remain in flight (wave-uniform n).
__device__ __forceinline__ void vmwait(int n) {
  switch (n) {
    case 0:  asm volatile("s_waitcnt vmcnt(0)"  ::: "memory"); return;
    case 1:  asm volatile("s_waitcnt vmcnt(1)"  ::: "memory"); return;
    case 2:  asm volatile("s_waitcnt vmcnt(2)"  ::: "memory"); return;
    case 3:  asm volatile("s_waitcnt vmcnt(3)"  ::: "memory"); return;
    case 4:  asm volatile("s_waitcnt vmcnt(4)"  ::: "memory"); return;
    case 5:  asm volatile("s_waitcnt vmcnt(5)"  ::: "memory"); return;
    case 6:  asm volatile("s_waitcnt vmcnt(6)"  ::: "memory"); return;
    case 7:  asm volatile("s_waitcnt vmcnt(7)"  ::: "memory"); return;
    case 8:  asm volatile("s_waitcnt vmcnt(8)"  ::: "memory"); return;
    case 9:  asm volatile("s_waitcnt vmcnt(9)"  ::: "memory"); return;
    case 10: asm volatile("s_waitcnt vmcnt(10)" ::: "memory"); return;
    case 11: asm volatile("s_waitcnt vmcnt(11)" ::: "memory"); return;
    case 12: asm volatile("s_waitcnt vmcnt(12)" ::: "memory"); return;
    case 14: asm volatile("s_waitcnt vmcnt(14)" ::: "memory"); return;
    case 16: asm volatile("s_waitcnt vmcnt(16)" ::: "memory"); return;
    case 20: asm volatile("s_waitcnt vmcnt(20)" ::: "memory"); return;
    default: asm volatile("s_waitcnt vmcnt(10)" ::: "memory"); return;
  }
}

// raw barrier (no implicit vmcnt(0) drain), pinned against scheduler motion
__device__ __forceinline__ void bar() {
  __builtin_amdgcn_sched_barrier(0);
  __builtin_amdgcn_s_barrier();
  __builtin_amdgcn_sched_barrier(0);
  asm volatile("" ::: "memory");
}

// ---------------------------------------------------------------------------
// prep: bn scale/bias folding.  s = g/sqrt(v+eps), beta = b - m*s.
// For the point-MLP bn, bo1 is folded in: beta_o = bo + (bo1 - mo)*s.
// ---------------------------------------------------------------------------
__global__ void prep_bn(const float* g1, const float* b1, const float* m1, const float* v1,
                        const float* g2, const float* b2, const float* m2, const float* v2,
                        const float* g3, const float* b3, const float* m3, const float* v3,
                        const float* go, const float* bo, const float* mo, const float* vo,
                        const float* bo1,
                        float* s1, float* be1, float* s2, float* be2,
                        float* s3, float* be3, float* so, float* beo) {
  int t = threadIdx.x;
  if (t < 256) { float s = g1[t] / sqrtf(v1[t] + EPS); s1[t] = s; be1[t] = b1[t] - m1[t] * s; }
  if (t < 64)  { float s = g2[t] / sqrtf(v2[t] + EPS); s2[t] = s; be2[t] = b2[t] - m2[t] * s; }
  if (t < 32)  { float s = g3[t] / sqrtf(v3[t] + EPS); s3[t] = s; be3[t] = b3[t] - m3[t] * s; }
  if (t < 32)  { float s = go[t] / sqrtf(vo[t] + EPS); so[t] = s; beo[t] = bo[t] + (bo1[t] - mo[t]) * s; }
}

// ---------------------------------------------------------------------------
// weight transform: W[co][ci][27] fp32 -> Wt[t][co][ci] bf16
// ---------------------------------------------------------------------------
__global__ void wtrans(const float* __restrict__ W, uint16_t* __restrict__ Wt,
                       int CO, int CI) {
  int idx = blockIdx.x * 256 + threadIdx.x;
  int total = CO * CI * 27;
  if (idx >= total) return;
  int t = idx / (CO * CI);
  int rem = idx % (CO * CI);
  int co = rem / CI, ci = rem % CI;
  Wt[idx] = f2bf(W[((size_t)co * CI + ci) * 27 + t]);
}

// ---------------------------------------------------------------------------
// halo zeroing: padded layout [nb][66][66][18][C] bf16; interior
// (d',h' in [1,64], w' in [1,16]) is fully overwritten by transpose/conv
// each iteration, so only halo voxels need zeros (~30MB vs 180MB memset).
// One block per (b,d',h') row of 18 voxels.
// ---------------------------------------------------------------------------
template <int C>
__global__ __launch_bounds__(256) void halo_zero(uint16_t* __restrict__ pad) {
  int id = blockIdx.x;
  int h = id % 66;
  int d = (id / 66) % 66;
  int b = id / (66 * 66);
  uint16_t* row = pad + ((size_t)b * 78408 + (size_t)(d * 1188 + h * 18)) * C;
  int tid = threadIdx.x;
  const uint4 z = make_uint4(0, 0, 0, 0);
  if (d == 0 || d == 65 || h == 0 || h == 65) {
    constexpr int n4 = 18 * C / 8;
    for (int i = tid; i < n4; i += 256) ((uint4*)row)[i] = z;
  } else {
    constexpr int n4 = C / 8;                     // w'=0 and w'=17 only
    if (tid < n4) ((uint4*)row)[tid] = z;
    else if (tid < 2 * n4) ((uint4*)(row + 17 * C))[tid - n4] = z;
  }
}

// ---------------------------------------------------------------------------
// fea NCDHW fp32 -> pad0 NDHWC bf16, padded dims [66][66][18][256].
// ---------------------------------------------------------------------------
__global__ __launch_bounds__(256) void transpose_fea(const float* __restrict__ fea,
                                                     uint16_t* __restrict__ pad0) {
  int tid = threadIdx.x;
  int idx = blockIdx.x;
  int half = idx & 1;
  int q = (idx >> 1) & 3;
  int d = (idx >> 3) & 63;
  int b = idx >> 9;
  int s = q * 256 + tid;               // h*16+w within the d-slice
  int h = s >> 4, w = s & 15;
  const float* src = fea + (size_t)(b * 256 + half * 128) * 65536 + (size_t)d * 1024 + s;
  uint16_t* dst = pad0 + ((size_t)b * 78408 +
                          (size_t)((d + 1) * 1188 + (h + 1) * 18 + (w + 1))) * 256 + half * 128;
#pragma unroll 4
  for (int c8 = 0; c8 < 16; ++c8) {
    uint16_t v[8];
#pragma unroll
    for (int j = 0; j < 8; ++j)
      v[j] = f2bf(src[(size_t)(c8 * 8 + j) * 65536]);
    *(uint4*)&dst[c8 * 8] = *(uint4*)v;
  }
}

// ---------------------------------------------------------------------------
// Implicit-GEMM 3x3x3 conv, NDHWC padded bf16, mfma_f32_16x16x32_bf16,
// fused BN+LeakyReLU.  MTILE=MH*16, NTILE=CO, 4 waves (WM x WN).
//
// ROUND-4 MODEL: rounds 0/2/3 (three different schedules) all show MFMA-busy
// ~210us invariant -> LDS-BANDWIDTH-bound, not latency-bound.  Read economy
// = Mw*Nw/(Mw+Nw) FLOP per LDS byte per wave; 64x128 waves give 42.7 ->
// demand ~130 B/cyc vs ~128 B/cyc capacity -> MfmaUtil pinned ~50%.
// Fix: 128x128 per-wave tiles (E=64 FLOP/B, demand ~84 B/cyc).  Costs 256
// acc VGPRs -> 1 wave/SIMD -> schedule must expose no latency:
//   per sub-epoch s (K=32):  stageB(s+1) -> [s==1: stageA(g+1)] ->
//   compute(s) -> vmwait -> s_barrier.
// One barrier per sub-epoch (stage targets buf[(s+1)&1], whose readers all
// passed the previous barrier).  Every load gets >=1 full compute phase
// (~1030cy) before its wait; A rides 2 sub-epochs (vmwait(aInstr) at s==1).
// OCC template arg: conv1/conv2 = 1 block/CU (big tiles), conv3 = 2.
// ---------------------------------------------------------------------------
template <int CI, int CO, int MH, int WM, int WN, int OCC, bool LAST>
__global__ __launch_bounds__(256, OCC) void conv_mfma(const uint16_t* __restrict__ padIn,
                                                      const uint16_t* __restrict__ Wt,
                                                      const float* __restrict__ bnS,
                                                      const float* __restrict__ bnB,
                                                      uint16_t* __restrict__ padOut,
                                                      float* __restrict__ x3out) {
  constexpr int NTILE = CO;
  constexpr int MTILE = MH * 16;
  constexpr int MPW = MTILE / WM;
  constexpr int NPW = NTILE / WN;
  constexpr int MSUB = MPW / 16;
  constexpr int NSUB = NPW / 16;
  constexpr int KC = CI / 64;
  constexpr int G = 9 * KC;
  constexpr int HB = 64 / MH;
  constexpr int HALF = MH / 8;
  constexpr int ROWSTR = 18 * CI;   // padded w-row stride (elements)

  __shared__ __align__(16) uint16_t Alds[2][18 * MH * 64];  // [w'0..17][mh][ci64]
  __shared__ __align__(16) uint16_t Blds[2][NTILE * 32];    // half-K [r>>1][r&1][u][8]

  const int tid = threadIdx.x;
  const int lane = tid & 63;
  const int wv = tid >> 6;
  const int wvm = wv / WN;
  const int wvn = wv % WN;
  const int col = lane & 15;
  const int quad = lane >> 4;

  const int mt = blockIdx.x;
  const int b = mt / (64 * HB);
  const int r = mt % (64 * HB);
  const int d = r / HB;
  const int h0 = (r % HB) * MH;

  const size_t bOffIn = (size_t)b * 78408 * CI;

  // B staging constants: thread tid -> (row rB within 64-row pass, stored slot q&3)
  const int qB = tid & 7;
  const int rB = ((tid >> 3) << 1) + (qB >> 2);
  const int uB = (qB & 3) ^ ((tid >> 3) & 3);   // global ci-unit fetched (pre-swizzle)

  // A staging: 18 slots over 4 waves -> {5,5,4,4}
  const int aslot0 = wv * 5 - (wv >= 2 ? (wv - 2) : 0);
  const int anslots = (wv < 2) ? 5 : 4;
  const int aInstr = anslots * HALF;

  auto stageA = [&](int dh, int kc, int as) {
    const int kd = dh / 3, kh = dh % 3;
    const uint16_t* agBase = padIn + bOffIn +
        (size_t)((d + kd) * 1188 + (h0 + kh) * 18) * CI + kc * 64 +
        (size_t)(lane >> 3) * ROWSTR;
    for (int p = 0; p < anslots; ++p) {
      int wp = aslot0 + p;
      int gu = (lane & 7) ^ (wp & 7);
#pragma unroll
      for (int hf = 0; hf < HALF; ++hf)
        g2lds16(agBase + (size_t)(hf * 8) * ROWSTR + wp * CI + gu * 8,
                (char*)Alds[as] + wp * (MH * 128) + hf * 1024);
    }
  };

  auto stageB = [&](int dh, int kc, int kw, int ks) {
    const uint16_t* bg = Wt + (size_t)((dh * 3 + kw) * CO) * CI + kc * 64 + ks * 32 + uB * 8;
    if constexpr (CO >= 64) {
#pragma unroll
      for (int p = 0; p < CO / 64; ++p)
        g2lds16(bg + (size_t)(rB + 64 * p) * CI, (char*)Blds[ks] + p * 4096 + wv * 1024);
    } else {
      if (tid < CO * 4)
        g2lds16(bg + (size_t)rB * CI, (char*)Blds[ks] + wv * 1024);
    }
  };

  f32x4 acc[MSUB][NSUB] = {};
  int acur = 0;

  auto compute = [&](int kw, int ks) {
    bf16x8 af[MSUB], bfr[NSUB];
#pragma unroll
    for (int mi = 0; mi < MSUB; ++mi) {
      int wq = col + kw;
      int u = (ks * 4 + quad) ^ (wq & 7);
      int mhIdx = wvm * MSUB + mi;
      af[mi] = *(const bf16x8*)&Alds[acur][wq * (MH * 64) + mhIdx * 64 + u * 8];
    }
#pragma unroll
    for (int ni = 0; ni < NSUB; ++ni) {
      int rw = wvn * NPW + ni * 16 + col;
      int u = quad ^ ((rw >> 1) & 3);
      bfr[ni] = *(const bf16x8*)&Blds[ks][(rw >> 1) * 64 + (rw & 1) * 32 + u * 8];
    }
    __builtin_amdgcn_s_setprio(1);
#pragma unroll
    for (int mi = 0; mi < MSUB; ++mi)
#pragma unroll
      for (int ni = 0; ni < NSUB; ++ni)
        acc[mi][ni] = __builtin_amdgcn_mfma_f32_16x16x32_bf16(af[mi], bfr[ni], acc[mi][ni], 0, 0, 0);
    __builtin_amdgcn_s_setprio(0);
  };

  // prologue: group 0's A + sub-epoch 0's B, one exposed drain
  stageA(0, 0, 0);
  stageB(0, 0, 0, 0);
  vmwait(0);
  bar();

  for (int g = 0; g < G; ++g) {
    const int dh = g / KC, kc = g % KC;
    const bool more = (g + 1 < G);
    const int dhn = (kc == KC - 1) ? dh + 1 : dh;
    const int kcn = (kc == KC - 1) ? 0 : kc + 1;
#pragma unroll
    for (int s = 0; s < 6; ++s) {
      const int kw = s >> 1, ks = s & 1;
      // stage next sub-epoch's B into buf[(s+1)&1] (its readers passed the
      // previous barrier) -- load rides across compute(s) before its wait.
      if (s < 5) stageB(dh, kc, (s + 1) >> 1, (s + 1) & 1);
      else if (more) stageB(dhn, kcn, 0, 0);
      // next group's A: issued at s==1, allowed to ride until s==2's wait
      // (~2 compute phases > HBM latency); A[acur^1] readers all finished
      // at group g's first barrier.
      if (s == 1 && more) stageA(dhn, kcn, acur ^ 1);
      compute(kw, ks);
      if (s == 5 && !more) break;          // last compute: no wait needed
      vmwait((s == 1 && more) ? aInstr : 0);
      bar();
    }
    acur ^= 1;
  }

  // epilogue: y = x*s + beta, LeakyReLU; C/D layout col=lane&15, row=quad*4+r
#pragma unroll
  for (int ni = 0; ni < NSUB; ++ni) {
    const int co = wvn * NPW + ni * 16 + col;
    const float sv = bnS[co];
    const float bv = bnB[co];
#pragma unroll
    for (int mi = 0; mi < MSUB; ++mi) {
#pragma unroll
      for (int rr = 0; rr < 4; ++rr) {
        int m = wvm * MPW + mi * 16 + quad * 4 + rr;
        float v = acc[mi][ni][rr] * sv + bv;
        v = v > 0.f ? v : SLOPE * v;
        int mh = m >> 4, w = m & 15;
        if (!LAST) {
          size_t o = ((size_t)b * 78408 +
                      (size_t)((d + 1) * 1188 + (h0 + mh + 1) * 18 + (w + 1))) * CO + co;
          padOut[o] = f2bf(v);
        } else {
          size_t o = ((size_t)b * 65536 + (size_t)((d * 64 + h0 + mh) * 16 + w)) * 32 + co;
          x3out[o] = v;
        }
      }
    }
  }
}

// ---------------------------------------------------------------------------
// gather + point MLP, all fp32. One thread per point.
// ---------------------------------------------------------------------------
__global__ __launch_bounds__(256) void gather_mlp(const float* __restrict__ x3,
                                                  const int* __restrict__ gidx,
                                                  const float* __restrict__ xyz,
                                                  const float* __restrict__ Wo1,
                                                  const float* __restrict__ so,
                                                  const float* __restrict__ beo,
                                                  const float* __restrict__ Wo2,
                                                  const float* __restrict__ bo2,
                                                  float* __restrict__ out) {
  __shared__ __align__(16) float w1[35 * 32];
  __shared__ float w2[32 * 3];
  __shared__ float sS[32], sB[32], b2s[3];
  int tid = threadIdx.x;
  for (int i = tid; i < 1120; i += 256) w1[i] = Wo1[i];
  if (tid < 96) w2[tid] = Wo2[tid];
  if (tid < 32) { sS[tid] = so[tid]; sB[tid] = beo[tid]; }
  if (tid < 3) b2s[tid] = bo2[tid];
  __syncthreads();

  int idx = blockIdx.x * 256 + tid;
  if (idx >= 200000) return;
  int b = idx >= 100000 ? 1 : 0;
  int gb = idx * 3;
  int i0 = gidx[gb], i1 = gidx[gb + 1], i2 = gidx[gb + 2];
  const float* pt = x3 + ((size_t)b * 65536 + (size_t)((i0 * 64 + i1) * 16 + i2)) * 32;

  float h[35];
#pragma unroll
  for (int q = 0; q < 8; ++q) {
    float4 v = *(const float4*)(pt + q * 4);
    h[q * 4] = v.x; h[q * 4 + 1] = v.y; h[q * 4 + 2] = v.z; h[q * 4 + 3] = v.w;
  }
  h[32] = xyz[gb]; h[33] = xyz[gb + 1]; h[34] = xyz[gb + 2];

  float a[32];
#pragma unroll
  for (int j = 0; j < 32; ++j) a[j] = 0.f;
#pragma unroll
  for (int k = 0; k < 35; ++k) {
    float hk = h[k];
    const float4* wr = (const float4*)(w1 + k * 32);
#pragma unroll
    for (int q = 0; q < 8; ++q) {
      float4 wv = wr[q];
      a[q * 4 + 0] += hk * wv.x;
      a[q * 4 + 1] += hk * wv.y;
      a[q * 4 + 2] += hk * wv.z;
      a[q * 4 + 3] += hk * wv.w;
    }
  }
  float o0 = b2s[0], o1 = b2s[1], o2 = b2s[2];
#pragma unroll
  for (int j = 0; j < 32; ++j) {
    float y = a[j] * sS[j] + sB[j];
    y = y > 0.f ? y : 0.f;
    o0 += y * w2[j * 3 + 0];
    o1 += y * w2[j * 3 + 1];
    o2 += y * w2[j * 3 + 2];
  }
  out[gb] = o0; out[gb + 1] = o1; out[gb + 2] = o2;
}

// ---------------------------------------------------------------------------
// workspace layout (bytes):
//   pad0: 0            .. 80,289,792   (2*78408*256*2)
//         [after conv1: pad2 @0 (20,072,448), x3 @20,072,448 (16,777,216)]
//   pad1: 80,289,792   .. 160,579,584
//   Wt1 : 160,579,584  (3,538,944)
//   Wt2 : 164,118,528  (884,736)
//   Wt3 : 165,003,264  (110,592)
//   bn  : 165,113,856  (8 slots x 1024B)
// total ~165.2 MB.  Halos zeroed by halo_zero (interiors fully overwritten
// every iteration by transpose/conv writes).
// ---------------------------------------------------------------------------
extern "C" void kernel_launch(void* const* d_in, const int* in_sizes, int n_in,
                              void* d_out, int out_size, void* d_ws, size_t ws_size,
                              hipStream_t stream) {
  (void)in_sizes; (void)n_in; (void)out_size;
  if (ws_size < 165130000) return;  // workspace too small — bail loudly (absmax will fail)

  const float* fea = (const float*)d_in[0];
  const int*   gidx = (const int*)d_in[1];
  const float* xyz = (const float*)d_in[2];
  const float* W1 = (const float*)d_in[3];
  const float* g1 = (const float*)d_in[4];
  const float* b1 = (const float*)d_in[5];
  const float* m1 = (const float*)d_in[6];
  const float* v1 = (const float*)d_in[7];
  const float* W2 = (const float*)d_in[8];
  const float* g2 = (const float*)d_in[9];
  const float* b2 = (const float*)d_in[10];
  const float* m2 = (const float*)d_in[11];
  const float* v2 = (const float*)d_in[12];
  const float* W3 = (const float*)d_in[13];
  const float* g3 = (const float*)d_in[14];
  const float* b3 = (const float*)d_in[15];
  const float* m3 = (const float*)d_in[16];
  const float* v3 = (const float*)d_in[17];
  const float* Wo1 = (const float*)d_in[18];
  const float* bo1 = (const float*)d_in[19];
  const float* go = (const float*)d_in[20];
  const float* bo = (const float*)d_in[21];
  const float* mo = (const float*)d_in[22];
  const float* vo = (const float*)d_in[23];
  const float* Wo2 = (const float*)d_in[24];
  const float* bo2 = (const float*)d_in[25];

  char* ws = (char*)d_ws;
  uint16_t* pad0 = (uint16_t*)(ws);
  uint16_t* pad1 = (uint16_t*)(ws + 80289792);
  uint16_t* Wt1 = (uint16_t*)(ws + 160579584);
  uint16_t* Wt2 = (uint16_t*)(ws + 164118528);
  uint16_t* Wt3 = (uint16_t*)(ws + 165003264);
  float* s1  = (float*)(ws + 165113856 + 0 * 1024);
  float* be1 = (float*)(ws + 165113856 + 1 * 1024);
  float* s2  = (float*)(ws + 165113856 + 2 * 1024);
  float* be2 = (float*)(ws + 165113856 + 3 * 1024);
  float* s3  = (float*)(ws + 165113856 + 4 * 1024);
  float* be3 = (float*)(ws + 165113856 + 5 * 1024);
  float* so  = (float*)(ws + 165113856 + 6 * 1024);
  float* beo = (float*)(ws + 165113856 + 7 * 1024);
  // aliases into pad0's region (pad0 is dead after conv1)
  uint16_t* pad2 = (uint16_t*)(ws);
  float* x3 = (float*)(ws + 20072448);

  prep_bn<<<1, 256, 0, stream>>>(g1, b1, m1, v1, g2, b2, m2, v2, g3, b3, m3, v3,
                                 go, bo, mo, vo, bo1, s1, be1, s2, be2, s3, be3, so, beo);
  wtrans<<<6912, 256, 0, stream>>>(W1, Wt1, 256, 256);
  wtrans<<<1728, 256, 0, stream>>>(W2, Wt2, 64, 256);
  wtrans<<<216, 256, 0, stream>>>(W3, Wt3, 32, 64);
  // pad0+pad1 halos (contiguous, same C=256: treat as 4 batches)
  halo_zero<256><<<17424, 256, 0, stream>>>(pad0);
  transpose_fea<<<1024, 256, 0, stream>>>(fea, pad0);

  // conv1: CI=256, CO=256, MH=16 (MTILE=256), waves 2x2, per-wave 128x128
  //        E=64 FLOP/LDS-byte; LDS 106,496 B -> 1 block/CU; grid 512 = 2
  //        exact sequential rounds per CU.
  conv_mfma<256, 256, 16, 2, 2, 1, false>
      <<<512, 256, 0, stream>>>(pad0, Wt1, s1, be1, pad1, nullptr);

  halo_zero<64><<<8712, 256, 0, stream>>>(pad2);  // pad2 halo (pad0 dead; stream-ordered)

  // conv2: CI=256, CO=64, MH=32 (MTILE=512), waves 4x1, per-wave 128x64
  //        E=42.7; LDS 155,648 B -> 1 block/CU; grid 256 = 1 block/CU exact.
  conv_mfma<256, 64, 32, 4, 1, 1, false>
      <<<256, 256, 0, stream>>>(pad1, Wt2, s2, be2, pad2, nullptr);

  // conv3: CI=64, CO=32, MH=16 (MTILE=256), waves 4x1, per-wave 64x32
  //        LDS 77,824 B -> 2 blocks/CU (small kernel, keep occupancy)
  conv_mfma<64, 32, 16, 4, 1, 2, true>
      <<<512, 256, 0, stream>>>(pad2, Wt3, s3, be3, nullptr, x3);

  gather_mlp<<<782, 256, 0, stream>>>(x3, gidx, xyz, Wo1, so, beo, Wo2, bo2, (float*)d_out);
}

// Round 5
// 1256.923 us; speedup vs baseline: 1.1067x; 1.1067x over previous
//
#include <hip/hip_runtime.h>
#include <stdint.h>

#define EPS 1e-5f
#define SLOPE 0.01f

typedef short bf16x8 __attribute__((ext_vector_type(8)));
typedef float f32x4 __attribute__((ext_vector_type(4)));

// round-to-nearest-even fp32 -> bf16
__device__ __forceinline__ uint16_t f2bf(float x) {
  union { float f; uint32_t u; } v; v.f = x;
  return (uint16_t)((v.u + 0x7fffu + ((v.u >> 16) & 1u)) >> 16);
}

// async global->LDS, 16B per lane; LDS dest = wave-uniform base + lane*16
__device__ __forceinline__ void g2lds16(const void* g, void* l) {
  __builtin_amdgcn_global_load_lds(
      (const __attribute__((address_space(1))) void*)g,
      (__attribute__((address_space(3))) void*)l, 16, 0, 0);
}

// counted vmem wait: allow n loads to remain in flight (wave-uniform n).
__device__ __forceinline__ void vmwait(int n) {
  switch (n) {
    case 0:  asm volatile("s_waitcnt vmcnt(0)"  ::: "memory"); return;
    case 1:  asm volatile("s_waitcnt vmcnt(1)"  ::: "memory"); return;
    case 2:  asm volatile("s_waitcnt vmcnt(2)"  ::: "memory"); return;
    case 3:  asm volatile("s_waitcnt vmcnt(3)"  ::: "memory"); return;
    case 4:  asm volatile("s_waitcnt vmcnt(4)"  ::: "memory"); return;
    case 5:  asm volatile("s_waitcnt vmcnt(5)"  ::: "memory"); return;
    case 6:  asm volatile("s_waitcnt vmcnt(6)"  ::: "memory"); return;
    case 7:  asm volatile("s_waitcnt vmcnt(7)"  ::: "memory"); return;
    case 8:  asm volatile("s_waitcnt vmcnt(8)"  ::: "memory"); return;
    case 9:  asm volatile("s_waitcnt vmcnt(9)"  ::: "memory"); return;
    case 10: asm volatile("s_waitcnt vmcnt(10)" ::: "memory"); return;
    case 11: asm volatile("s_waitcnt vmcnt(11)" ::: "memory"); return;
    case 12: asm volatile("s_waitcnt vmcnt(12)" ::: "memory"); return;
    case 13: asm volatile("s_waitcnt vmcnt(13)" ::: "memory"); return;
    case 14: asm volatile("s_waitcnt vmcnt(14)" ::: "memory"); return;
    case 15: asm volatile("s_waitcnt vmcnt(15)" ::: "memory"); return;
    default: asm volatile("s_waitcnt vmcnt(16)" ::: "memory"); return;
  }
}

// raw barrier (no implicit vmcnt(0) drain), pinned against scheduler motion
__device__ __forceinline__ void bar() {
  __builtin_amdgcn_sched_barrier(0);
  __builtin_amdgcn_s_barrier();
  __builtin_amdgcn_sched_barrier(0);
  asm volatile("" ::: "memory");
}

// ---------------------------------------------------------------------------
// prep: bn scale/bias folding.  s = g/sqrt(v+eps), beta = b - m*s.
// For the point-MLP bn, bo1 is folded in: beta_o = bo + (bo1 - mo)*s.
// ---------------------------------------------------------------------------
__global__ void prep_bn(const float* g1, const float* b1, const float* m1, const float* v1,
                        const float* g2, const float* b2, const float* m2, const float* v2,
                        const float* g3, const float* b3, const float* m3, const float* v3,
                        const float* go, const float* bo, const float* mo, const float* vo,
                        const float* bo1,
                        float* s1, float* be1, float* s2, float* be2,
                        float* s3, float* be3, float* so, float* beo) {
  int t = threadIdx.x;
  if (t < 256) { float s = g1[t] / sqrtf(v1[t] + EPS); s1[t] = s; be1[t] = b1[t] - m1[t] * s; }
  if (t < 64)  { float s = g2[t] / sqrtf(v2[t] + EPS); s2[t] = s; be2[t] = b2[t] - m2[t] * s; }
  if (t < 32)  { float s = g3[t] / sqrtf(v3[t] + EPS); s3[t] = s; be3[t] = b3[t] - m3[t] * s; }
  if (t < 32)  { float s = go[t] / sqrtf(vo[t] + EPS); so[t] = s; beo[t] = bo[t] + (bo1[t] - mo[t]) * s; }
}

// ---------------------------------------------------------------------------
// weight transform: W[co][ci][27] fp32 -> Wt[t][co][ci] bf16
// ---------------------------------------------------------------------------
__global__ void wtrans(const float* __restrict__ W, uint16_t* __restrict__ Wt,
                       int CO, int CI) {
  int idx = blockIdx.x * 256 + threadIdx.x;
  int total = CO * CI * 27;
  if (idx >= total) return;
  int t = idx / (CO * CI);
  int rem = idx % (CO * CI);
  int co = rem / CI, ci = rem % CI;
  Wt[idx] = f2bf(W[((size_t)co * CI + ci) * 27 + t]);
}

// ---------------------------------------------------------------------------
// halo zeroing: padded layout [nb][66][66][18][C] bf16; interior fully
// overwritten by transpose/conv each iteration -> only halo needs zeros.
// ---------------------------------------------------------------------------
template <int C>
__global__ __launch_bounds__(256) void halo_zero(uint16_t* __restrict__ pad) {
  int id = blockIdx.x;
  int h = id % 66;
  int d = (id / 66) % 66;
  int b = id / (66 * 66);
  uint16_t* row = pad + ((size_t)b * 78408 + (size_t)(d * 1188 + h * 18)) * C;
  int tid = threadIdx.x;
  const uint4 z = make_uint4(0, 0, 0, 0);
  if (d == 0 || d == 65 || h == 0 || h == 65) {
    constexpr int n4 = 18 * C / 8;
    for (int i = tid; i < n4; i += 256) ((uint4*)row)[i] = z;
  } else {
    constexpr int n4 = C / 8;                     // w'=0 and w'=17 only
    if (tid < n4) ((uint4*)row)[tid] = z;
    else if (tid < 2 * n4) ((uint4*)(row + 17 * C))[tid - n4] = z;
  }
}

// ---------------------------------------------------------------------------
// fea NCDHW fp32 -> pad0 NDHWC bf16, padded dims [66][66][18][256].
// ---------------------------------------------------------------------------
__global__ __launch_bounds__(256) void transpose_fea(const float* __restrict__ fea,
                                                     uint16_t* __restrict__ pad0) {
  int tid = threadIdx.x;
  int idx = blockIdx.x;
  int half = idx & 1;
  int q = (idx >> 1) & 3;
  int d = (idx >> 3) & 63;
  int b = idx >> 9;
  int s = q * 256 + tid;               // h*16+w within the d-slice
  int h = s >> 4, w = s & 15;
  const float* src = fea + (size_t)(b * 256 + half * 128) * 65536 + (size_t)d * 1024 + s;
  uint16_t* dst = pad0 + ((size_t)b * 78408 +
                          (size_t)((d + 1) * 1188 + (h + 1) * 18 + (w + 1))) * 256 + half * 128;
#pragma unroll 4
  for (int c8 = 0; c8 < 16; ++c8) {
    uint16_t v[8];
#pragma unroll
    for (int j = 0; j < 8; ++j)
      v[j] = f2bf(src[(size_t)(c8 * 8 + j) * 65536]);
    *(uint4*)&dst[c8 * 8] = *(uint4*)v;
  }
}

// ---------------------------------------------------------------------------
// Implicit-GEMM 3x3x3 conv, NDHWC padded bf16, mfma_f32_16x16x32_bf16,
// fused BN+LeakyReLU.  ROUND-5: m201-class 8-wave structure.
//
// 512 threads, 8 waves (WM x WN), block tile MTILE x CO, per-wave acc <= 128
// regs (rounds 0-3 proven safe; round 4's 256 spilled).  1 block/CU,
// 2 waves/SIMD -- m201's occupancy class (62% MfmaUtil at this same
// per-wave LDS economy).
//
// Schedule per sub-epoch t (6 per (dh,kc) group, K=32 each), B ring-3:
//   stage B(t+2) -> buf[(t+2)%3]        (flies ~2 sub-epochs)
//   [s==4: stage A(next group) -> A[acur^1]]  (flies ~1.5 sub-epochs)
//   ds_read fragments(t) from buf[t%3], A[acur]   (data retired at wait(t-1))
//   vmwait(allow)   allow = bInstr (+aInstr at s==4)   -- NEVER 0 mid-loop
//   bar ; MFMA(t) in setprio(1) ; bar
// FIFO audit: wait(t) retires exactly B(t+1) (needed by reads(t+1)); the
// A batch issued after B at s==4 is force-retired by s==5's wait (B(t+1)
// there is younger than A), one sub-epoch before its first read. Writes to
// buf[t%3] (staged at t+1) are >= 2 barriers after reads(t) complete.
// ---------------------------------------------------------------------------
template <int CI, int CO, int MH, int WM, int WN, bool LAST>
__global__ __launch_bounds__(512, 2) void conv_mfma(const uint16_t* __restrict__ padIn,
                                                    const uint16_t* __restrict__ Wt,
                                                    const float* __restrict__ bnS,
                                                    const float* __restrict__ bnB,
                                                    uint16_t* __restrict__ padOut,
                                                    float* __restrict__ x3out) {
  constexpr int WAVES = WM * WN;                 // 8
  constexpr int NTILE = CO;
  constexpr int MTILE = MH * 16;
  constexpr int MPW = MTILE / WM;
  constexpr int NPW = NTILE / WN;
  constexpr int MSUB = MPW / 16;
  constexpr int NSUB = NPW / 16;
  constexpr int KC = CI / 64;
  constexpr int G = 9 * KC;
  constexpr int HB = 64 / MH;
  constexpr int HALF = MH / 8;
  constexpr int ROWSTR = 18 * CI;                // padded w-row stride (elements)
  constexpr int PASSROWS = 128;                  // 512 thr * 16B / 64B-row
  constexpr int ABASE = 18 / WAVES, AREM = 18 % WAVES;

  __shared__ __align__(16) uint16_t Alds[2][18 * MH * 64];  // [w'0..17][mh][ci64]
  __shared__ __align__(16) uint16_t Blds[3][NTILE * 32];    // ring-3 half-K

  const int tid = threadIdx.x;
  const int lane = tid & 63;
  const int wv = tid >> 6;
  const int wvm = wv / WN;
  const int wvn = wv % WN;
  const int col = lane & 15;
  const int quad = lane >> 4;

  const int mt = blockIdx.x;
  const int b = mt / (64 * HB);
  const int r = mt % (64 * HB);
  const int d = r / HB;
  const int h0 = (r % HB) * MH;

  const size_t bOffIn = (size_t)b * 78408 * CI;

  // B staging: thread tid covers global row rB (within a 128-row pass),
  // fetching ci-unit uB into stored slot (tid&3); XOR swizzle by row-pair.
  const int jB = tid & 7;
  const int rB = ((tid >> 3) << 1) + (jB >> 2);
  const int uB = (jB & 3) ^ ((tid >> 3) & 3);

  // A staging: 18 slots over 8 waves -> {3,3,2,2,2,2,2,2}
  const int aslot0 = (wv < AREM) ? wv * (ABASE + 1)
                                 : AREM * (ABASE + 1) + (wv - AREM) * ABASE;
  const int anslots = (wv < AREM) ? ABASE + 1 : ABASE;
  const int aInstr = anslots * HALF;
  const int bInstr = (CO >= PASSROWS) ? (CO / PASSROWS) : ((wv * 64 < CO * 4) ? 1 : 0);

  auto stageA = [&](int g, int as) {
    const int dh = g / KC, kc = g % KC;
    const int kd = dh / 3, kh = dh % 3;
    const uint16_t* agBase = padIn + bOffIn +
        (size_t)((d + kd) * 1188 + (h0 + kh) * 18) * CI + kc * 64 +
        (size_t)(lane >> 3) * ROWSTR;
    for (int p = 0; p < anslots; ++p) {
      int wp = aslot0 + p;
      int gu = (lane & 7) ^ (wp & 7);
#pragma unroll
      for (int hf = 0; hf < HALF; ++hf)
        g2lds16(agBase + (size_t)(hf * 8) * ROWSTR + wp * CI + gu * 8,
                (char*)Alds[as] + wp * (MH * 128) + hf * 1024);
    }
  };

  auto stageB = [&](int g, int s, int bi) {
    const int dh = g / KC, kc = g % KC;
    const int kw = s >> 1, ks = s & 1;
    const uint16_t* bg = Wt + (size_t)((dh * 3 + kw) * CO) * CI + kc * 64 + ks * 32 + uB * 8;
    if constexpr (CO >= PASSROWS) {
#pragma unroll
      for (int p = 0; p < CO / PASSROWS; ++p)
        g2lds16(bg + (size_t)(rB + PASSROWS * p) * CI,
                (char*)Blds[bi] + p * (PASSROWS * 64) + wv * 1024);
    } else {
      if (tid < CO * 4)
        g2lds16(bg + (size_t)rB * CI, (char*)Blds[bi] + wv * 1024);
    }
  };

  f32x4 acc[MSUB][NSUB] = {};
  int acur = 0;

  // prologue: A(0), B(t=0), B(t=1); retire A0+B0, let B1 fly
  stageA(0, 0);
  stageB(0, 0, 0);
  stageB(0, 1, 1);
  vmwait(bInstr);
  bar();

  for (int g = 0; g < G; ++g) {
    const bool more = (g + 1 < G);
#pragma unroll
    for (int s = 0; s < 6; ++s) {
      const int kw = s >> 1, ks = s & 1;
      constexpr int BI2[6] = {2, 0, 1, 2, 0, 1};   // (s+2)%3
      constexpr int BI[6]  = {0, 1, 2, 0, 1, 2};   // s%3
      // stage B two sub-epochs ahead
      if (s < 4) stageB(g, s + 2, BI2[s]);
      else if (more) stageB(g + 1, s - 4, BI2[s]);
      // stage next group's A (after B -> A is younger, survives s==4's wait)
      if (s == 4 && more) stageA(g + 1, acur ^ 1);
      // fragment reads for THIS sub-epoch (data retired at previous wait)
      bf16x8 af[MSUB], bfr[NSUB];
#pragma unroll
      for (int mi = 0; mi < MSUB; ++mi) {
        int wq = col + kw;
        int u = (ks * 4 + quad) ^ (wq & 7);
        int mhIdx = wvm * MSUB + mi;
        af[mi] = *(const bf16x8*)&Alds[acur][wq * (MH * 64) + mhIdx * 64 + u * 8];
      }
#pragma unroll
      for (int ni = 0; ni < NSUB; ++ni) {
        int rw = wvn * NPW + ni * 16 + col;
        int u = quad ^ ((rw >> 1) & 3);
        bfr[ni] = *(const bf16x8*)&Blds[BI[s]][(rw >> 1) * 64 + (rw & 1) * 32 + u * 8];
      }
      // counted wait: retire stage(t+1)'s data batch; keep younger in flight
      {
        int allow = 0;
        if (s < 4 || more) allow += bInstr;
        if (s == 4 && more) allow += aInstr;
        vmwait(allow);
      }
      bar();
      __builtin_amdgcn_s_setprio(1);
#pragma unroll
      for (int mi = 0; mi < MSUB; ++mi)
#pragma unroll
        for (int ni = 0; ni < NSUB; ++ni)
          acc[mi][ni] = __builtin_amdgcn_mfma_f32_16x16x32_bf16(af[mi], bfr[ni], acc[mi][ni], 0, 0, 0);
      __builtin_amdgcn_s_setprio(0);
      bar();
    }
    acur ^= 1;
  }

  // epilogue: y = x*s + beta, LeakyReLU; C/D layout col=lane&15, row=quad*4+r
#pragma unroll
  for (int ni = 0; ni < NSUB; ++ni) {
    const int co = wvn * NPW + ni * 16 + col;
    const float sv = bnS[co];
    const float bv = bnB[co];
#pragma unroll
    for (int mi = 0; mi < MSUB; ++mi) {
#pragma unroll
      for (int rr = 0; rr < 4; ++rr) {
        int m = wvm * MPW + mi * 16 + quad * 4 + rr;
        float v = acc[mi][ni][rr] * sv + bv;
        v = v > 0.f ? v : SLOPE * v;
        int mh = m >> 4, w = m & 15;
        if (!LAST) {
          size_t o = ((size_t)b * 78408 +
                      (size_t)((d + 1) * 1188 + (h0 + mh + 1) * 18 + (w + 1))) * CO + co;
          padOut[o] = f2bf(v);
        } else {
          size_t o = ((size_t)b * 65536 + (size_t)((d * 64 + h0 + mh) * 16 + w)) * 32 + co;
          x3out[o] = v;
        }
      }
    }
  }
}

// ---------------------------------------------------------------------------
// gather + point MLP, all fp32. One thread per point.
// ---------------------------------------------------------------------------
__global__ __launch_bounds__(256) void gather_mlp(const float* __restrict__ x3,
                                                  const int* __restrict__ gidx,
                                                  const float* __restrict__ xyz,
                                                  const float* __restrict__ Wo1,
                                                  const float* __restrict__ so,
                                                  const float* __restrict__ beo,
                                                  const float* __restrict__ Wo2,
                                                  const float* __restrict__ bo2,
                                                  float* __restrict__ out) {
  __shared__ __align__(16) float w1[35 * 32];
  __shared__ float w2[32 * 3];
  __shared__ float sS[32], sB[32], b2s[3];
  int tid = threadIdx.x;
  for (int i = tid; i < 1120; i += 256) w1[i] = Wo1[i];
  if (tid < 96) w2[tid] = Wo2[tid];
  if (tid < 32) { sS[tid] = so[tid]; sB[tid] = beo[tid]; }
  if (tid < 3) b2s[tid] = bo2[tid];
  __syncthreads();

  int idx = blockIdx.x * 256 + tid;
  if (idx >= 200000) return;
  int b = idx >= 100000 ? 1 : 0;
  int gb = idx * 3;
  int i0 = gidx[gb], i1 = gidx[gb + 1], i2 = gidx[gb + 2];
  const float* pt = x3 + ((size_t)b * 65536 + (size_t)((i0 * 64 + i1) * 16 + i2)) * 32;

  float h[35];
#pragma unroll
  for (int q = 0; q < 8; ++q) {
    float4 v = *(const float4*)(pt + q * 4);
    h[q * 4] = v.x; h[q * 4 + 1] = v.y; h[q * 4 + 2] = v.z; h[q * 4 + 3] = v.w;
  }
  h[32] = xyz[gb]; h[33] = xyz[gb + 1]; h[34] = xyz[gb + 2];

  float a[32];
#pragma unroll
  for (int j = 0; j < 32; ++j) a[j] = 0.f;
#pragma unroll
  for (int k = 0; k < 35; ++k) {
    float hk = h[k];
    const float4* wr = (const float4*)(w1 + k * 32);
#pragma unroll
    for (int q = 0; q < 8; ++q) {
      float4 wv = wr[q];
      a[q * 4 + 0] += hk * wv.x;
      a[q * 4 + 1] += hk * wv.y;
      a[q * 4 + 2] += hk * wv.z;
      a[q * 4 + 3] += hk * wv.w;
    }
  }
  float o0 = b2s[0], o1 = b2s[1], o2 = b2s[2];
#pragma unroll
  for (int j = 0; j < 32; ++j) {
    float y = a[j] * sS[j] + sB[j];
    y = y > 0.f ? y : 0.f;
    o0 += y * w2[j * 3 + 0];
    o1 += y * w2[j * 3 + 1];
    o2 += y * w2[j * 3 + 2];
  }
  out[gb] = o0; out[gb + 1] = o1; out[gb + 2] = o2;
}

// ---------------------------------------------------------------------------
// workspace layout (bytes):
//   pad0: 0            .. 80,289,792   (2*78408*256*2)
//         [after conv1: pad2 @0 (20,072,448), x3 @20,072,448 (16,777,216)]
//   pad1: 80,289,792   .. 160,579,584
//   Wt1 : 160,579,584  (3,538,944)
//   Wt2 : 164,118,528  (884,736)
//   Wt3 : 165,003,264  (110,592)
//   bn  : 165,113,856  (8 slots x 1024B)
// total ~165.2 MB.  Halos zeroed by halo_zero.
// ---------------------------------------------------------------------------
extern "C" void kernel_launch(void* const* d_in, const int* in_sizes, int n_in,
                              void* d_out, int out_size, void* d_ws, size_t ws_size,
                              hipStream_t stream) {
  (void)in_sizes; (void)n_in; (void)out_size;
  if (ws_size < 165130000) return;  // workspace too small — bail loudly (absmax will fail)

  const float* fea = (const float*)d_in[0];
  const int*   gidx = (const int*)d_in[1];
  const float* xyz = (const float*)d_in[2];
  const float* W1 = (const float*)d_in[3];
  const float* g1 = (const float*)d_in[4];
  const float* b1 = (const float*)d_in[5];
  const float* m1 = (const float*)d_in[6];
  const float* v1 = (const float*)d_in[7];
  const float* W2 = (const float*)d_in[8];
  const float* g2 = (const float*)d_in[9];
  const float* b2 = (const float*)d_in[10];
  const float* m2 = (const float*)d_in[11];
  const float* v2 = (const float*)d_in[12];
  const float* W3 = (const float*)d_in[13];
  const float* g3 = (const float*)d_in[14];
  const float* b3 = (const float*)d_in[15];
  const float* m3 = (const float*)d_in[16];
  const float* v3 = (const float*)d_in[17];
  const float* Wo1 = (const float*)d_in[18];
  const float* bo1 = (const float*)d_in[19];
  const float* go = (const float*)d_in[20];
  const float* bo = (const float*)d_in[21];
  const float* mo = (const float*)d_in[22];
  const float* vo = (const float*)d_in[23];
  const float* Wo2 = (const float*)d_in[24];
  const float* bo2 = (const float*)d_in[25];

  char* ws = (char*)d_ws;
  uint16_t* pad0 = (uint16_t*)(ws);
  uint16_t* pad1 = (uint16_t*)(ws + 80289792);
  uint16_t* Wt1 = (uint16_t*)(ws + 160579584);
  uint16_t* Wt2 = (uint16_t*)(ws + 164118528);
  uint16_t* Wt3 = (uint16_t*)(ws + 165003264);
  float* s1  = (float*)(ws + 165113856 + 0 * 1024);
  float* be1 = (float*)(ws + 165113856 + 1 * 1024);
  float* s2  = (float*)(ws + 165113856 + 2 * 1024);
  float* be2 = (float*)(ws + 165113856 + 3 * 1024);
  float* s3  = (float*)(ws + 165113856 + 4 * 1024);
  float* be3 = (float*)(ws + 165113856 + 5 * 1024);
  float* so  = (float*)(ws + 165113856 + 6 * 1024);
  float* beo = (float*)(ws + 165113856 + 7 * 1024);
  // aliases into pad0's region (pad0 is dead after conv1)
  uint16_t* pad2 = (uint16_t*)(ws);
  float* x3 = (float*)(ws + 20072448);

  prep_bn<<<1, 256, 0, stream>>>(g1, b1, m1, v1, g2, b2, m2, v2, g3, b3, m3, v3,
                                 go, bo, mo, vo, bo1, s1, be1, s2, be2, s3, be3, so, beo);
  wtrans<<<6912, 256, 0, stream>>>(W1, Wt1, 256, 256);
  wtrans<<<1728, 256, 0, stream>>>(W2, Wt2, 64, 256);
  wtrans<<<216, 256, 0, stream>>>(W3, Wt3, 32, 64);
  // pad0+pad1 halos (contiguous, same C=256: treat as 4 batches)
  halo_zero<256><<<17424, 256, 0, stream>>>(pad0);
  transpose_fea<<<1024, 256, 0, stream>>>(fea, pad0);

  // conv1: CI=256, CO=256, MTILE=256 (MH=16), 8 waves 2x4, per-wave 128x64
  //        (acc 128 = proven-safe).  LDS 122,880 -> 1 block/CU, 2 waves/SIMD.
  //        grid 512 = 2 exact generations.
  conv_mfma<256, 256, 16, 2, 4, false>
      <<<512, 512, 0, stream>>>(pad0, Wt1, s1, be1, pad1, nullptr);

  halo_zero<64><<<8712, 256, 0, stream>>>(pad2);  // pad2 halo (pad0 dead; stream-ordered)

  // conv2: CI=256, CO=64, MTILE=512 (MH=32), 8 waves 8x1, per-wave 64x64
  //        LDS 159,744 -> 1 block/CU; grid 256 = 1 generation.
  conv_mfma<256, 64, 32, 8, 1, false>
      <<<256, 512, 0, stream>>>(pad1, Wt2, s2, be2, pad2, nullptr);

  // conv3: CI=64, CO=32, MTILE=512 (MH=32), 8 waves 8x1, per-wave 64x32
  //        LDS 153,600 -> 1 block/CU; grid 256.
  conv_mfma<64, 32, 32, 8, 1, true>
      <<<256, 512, 0, stream>>>(pad2, Wt3, s3, be3, nullptr, x3);

  gather_mlp<<<782, 256, 0, stream>>>(x3, gidx, xyz, Wo1, so, beo, Wo2, bo2, (float*)d_out);
}

// Round 7
// 1042.843 us; speedup vs baseline: 1.3338x; 1.2053x over previous
//
#include <hip/hip_runtime.h>
#include <stdint.h>

#define EPS 1e-5f
#define SLOPE 0.01f

typedef short bf16x8 __attribute__((ext_vector_type(8)));
typedef float f32x4 __attribute__((ext_vector_type(4)));

// round-to-nearest-even fp32 -> bf16
__device__ __forceinline__ uint16_t f2bf(float x) {
  union { float f; uint32_t u; } v; v.f = x;
  return (uint16_t)((v.u + 0x7fffu + ((v.u >> 16) & 1u)) >> 16);
}

// async global->LDS, 16B per lane; LDS dest = wave-uniform base + lane*16
__device__ __forceinline__ void g2lds16(const void* g, void* l) {
  __builtin_amdgcn_global_load_lds(
      (const __attribute__((address_space(1))) void*)g,
      (__attribute__((address_space(3))) void*)l, 16, 0, 0);
}

// ---------------------------------------------------------------------------
// prep: bn scale/bias folding.  s = g/sqrt(v+eps), beta = b - m*s.
// For the point-MLP bn, bo1 is folded in: beta_o = bo + (bo1 - mo)*s.
// ---------------------------------------------------------------------------
__global__ void prep_bn(const float* g1, const float* b1, const float* m1, const float* v1,
                        const float* g2, const float* b2, const float* m2, const float* v2,
                        const float* g3, const float* b3, const float* m3, const float* v3,
                        const float* go, const float* bo, const float* mo, const float* vo,
                        const float* bo1,
                        float* s1, float* be1, float* s2, float* be2,
                        float* s3, float* be3, float* so, float* beo) {
  int t = threadIdx.x;
  if (t < 256) { float s = g1[t] / sqrtf(v1[t] + EPS); s1[t] = s; be1[t] = b1[t] - m1[t] * s; }
  if (t < 64)  { float s = g2[t] / sqrtf(v2[t] + EPS); s2[t] = s; be2[t] = b2[t] - m2[t] * s; }
  if (t < 32)  { float s = g3[t] / sqrtf(v3[t] + EPS); s3[t] = s; be3[t] = b3[t] - m3[t] * s; }
  if (t < 32)  { float s = go[t] / sqrtf(vo[t] + EPS); so[t] = s; beo[t] = bo[t] + (bo1[t] - mo[t]) * s; }
}

// ---------------------------------------------------------------------------
// weight transform: W[co][ci][27] fp32 -> Wt[t][co][ci] bf16
// ---------------------------------------------------------------------------
__global__ void wtrans(const float* __restrict__ W, uint16_t* __restrict__ Wt,
                       int CO, int CI) {
  int idx = blockIdx.x * 256 + threadIdx.x;
  int total = CO * CI * 27;
  if (idx >= total) return;
  int t = idx / (CO * CI);
  int rem = idx % (CO * CI);
  int co = rem / CI, ci = rem % CI;
  Wt[idx] = f2bf(W[((size_t)co * CI + ci) * 27 + t]);
}

// ---------------------------------------------------------------------------
// halo zeroing: padded layout [nb][66][66][18][C] bf16; interior fully
// overwritten by transpose/conv/reduce each iteration -> only halo needs
// zeros (~30MB vs 180MB memset).  One block per (b,d',h') row of 18 voxels.
// ---------------------------------------------------------------------------
template <int C>
__global__ __launch_bounds__(256) void halo_zero(uint16_t* __restrict__ pad) {
  int id = blockIdx.x;
  int h = id % 66;
  int d = (id / 66) % 66;
  int b = id / (66 * 66);
  uint16_t* row = pad + ((size_t)b * 78408 + (size_t)(d * 1188 + h * 18)) * C;
  int tid = threadIdx.x;
  const uint4 z = make_uint4(0, 0, 0, 0);
  if (d == 0 || d == 65 || h == 0 || h == 65) {
    constexpr int n4 = 18 * C / 8;
    for (int i = tid; i < n4; i += 256) ((uint4*)row)[i] = z;
  } else {
    constexpr int n4 = C / 8;                     // w'=0 and w'=17 only
    if (tid < n4) ((uint4*)row)[tid] = z;
    else if (tid < 2 * n4) ((uint4*)(row + 17 * C))[tid - n4] = z;
  }
}

// ---------------------------------------------------------------------------
// fea NCDHW fp32 -> pad0 NDHWC bf16, padded dims [66][66][18][256].
// ---------------------------------------------------------------------------
__global__ __launch_bounds__(256) void transpose_fea(const float* __restrict__ fea,
                                                     uint16_t* __restrict__ pad0) {
  int tid = threadIdx.x;
  int idx = blockIdx.x;
  int half = idx & 1;
  int q = (idx >> 1) & 3;
  int d = (idx >> 3) & 63;
  int b = idx >> 9;
  int s = q * 256 + tid;               // h*16+w within the d-slice
  int h = s >> 4, w = s & 15;
  const float* src = fea + (size_t)(b * 256 + half * 128) * 65536 + (size_t)d * 1024 + s;
  uint16_t* dst = pad0 + ((size_t)b * 78408 +
                          (size_t)((d + 1) * 1188 + (h + 1) * 18 + (w + 1))) * 256 + half * 128;
#pragma unroll 4
  for (int c8 = 0; c8 < 16; ++c8) {
    uint16_t v[8];
#pragma unroll
    for (int j = 0; j < 8; ++j)
      v[j] = f2bf(src[(size_t)(c8 * 8 + j) * 65536]);
    *(uint4*)&dst[c8 * 8] = *(uint4*)v;
  }
}

// ---------------------------------------------------------------------------
// Implicit-GEMM 3x3x3 conv, NDHWC padded bf16, mfma_f32_16x16x32_bf16.
// EXACT round-0 structure (proven 400us conv1 @ 52% MfmaUtil, 2 blocks/CU
// inter-block overlap = the load-bearing mechanism, m114).  Model post-R5:
// this structure sits within ~8% of its LDS-throughput ceiling at the
// 128-acc-register budget -- do not touch the inner loop.
// Additions are orthogonal: kc-range [KC0, KC0+KCN) for split-K (conv2),
// OCC for occupancy hint, OMODE for epilogue:
//   0 = padded bf16 out, BN+LeakyReLU   (conv1)
//   1 = linear f32 out,  BN+LeakyReLU   (conv3 -> x3)
//   2 = linear f32 out,  RAW partial    (conv2 split-K halves)
// ---------------------------------------------------------------------------
template <int CI, int CO, int MH, int WM, int WN, int KC0, int KCN, int OCC, int OMODE>
__global__ __launch_bounds__(256, OCC) void conv_mfma(const uint16_t* __restrict__ padIn,
                                                      const uint16_t* __restrict__ Wt,
                                                      const float* __restrict__ bnS,
                                                      const float* __restrict__ bnB,
                                                      uint16_t* __restrict__ padOut,
                                                      float* __restrict__ fOut) {
  constexpr int NTILE = CO;
  constexpr int MTILE = MH * 16;
  constexpr int MPW = MTILE / WM;
  constexpr int NPW = NTILE / WN;
  constexpr int MSUB = MPW / 16;
  constexpr int NSUB = NPW / 16;
  constexpr int BPASS = NTILE / 32;
  constexpr int HB = 64 / MH;
  constexpr int HALF = MH / 8;
  constexpr int ROWSTR = 18 * CI;   // padded w-row stride (elements)

  __shared__ __align__(16) uint16_t Alds[20 * MH * 64];  // [w'][mh][ci64]; w' 18,19 dummy
  __shared__ __align__(16) uint16_t Blds[NTILE * 64];    // [n][ci64]

  const int tid = threadIdx.x;
  const int lane = tid & 63;
  const int wv = tid >> 6;
  const int wvm = wv / WN;
  const int wvn = wv % WN;

  const int mt = blockIdx.x;
  const int b = mt / (64 * HB);
  const int r = mt % (64 * HB);
  const int d = r / HB;
  const int h0 = (r % HB) * MH;

  // B staging constants
  const int subswB = (tid & 7) ^ ((tid >> 3) & 7);
  const int rowB0 = tid >> 3;

  f32x4 acc[MSUB][NSUB] = {};

  const size_t bOffIn = (size_t)b * 78408 * CI;

  for (int dh = 0; dh < 9; ++dh) {
    const int kd = dh / 3, kh = dh % 3;
    const size_t Abase = bOffIn + (size_t)((d + kd) * 1188 + (h0 + kh) * 18) * CI;
    for (int kc = KC0; kc < KC0 + KCN; ++kc) {
      for (int kw = 0; kw < 3; ++kw) {
        __syncthreads();  // previous epoch's LDS reads done
        if (kw == 0) {
          // stage A_ext: wave wv covers w'-slots wv*5..wv*5+4 (20 incl. dummies),
          // each slot = HALF instrs of (8 mh-rows x 128B), lanes: mh=lane>>3, unit=lane&7
          const uint16_t* agBase = padIn + Abase + kc * 64 + (size_t)(lane >> 3) * ROWSTR;
#pragma unroll
          for (int p = 0; p < 5; ++p) {
            int wp = wv * 5 + p;
            int gu = (lane & 7) ^ (wp & 7);
#pragma unroll
            for (int hf = 0; hf < HALF; ++hf)
              g2lds16(agBase + (size_t)(hf * 8) * ROWSTR + wp * CI + gu * 8,
                      (char*)Alds + wp * (MH * 128) + hf * 1024);
          }
        }
        {
          const uint16_t* bg = Wt + (size_t)((dh * 3 + kw) * CO) * CI + kc * 64 + subswB * 8;
#pragma unroll
          for (int p = 0; p < BPASS; ++p)
            g2lds16(bg + (size_t)(rowB0 + 32 * p) * CI, (char*)Blds + p * 4096 + wv * 1024);
        }
        __syncthreads();  // staging DMA drained
#pragma unroll
        for (int ks = 0; ks < 2; ++ks) {
          bf16x8 af[MSUB], bfr[NSUB];
#pragma unroll
          for (int mi = 0; mi < MSUB; ++mi) {
            int wq = (lane & 15) + kw;
            int u = (ks * 4 + (lane >> 4)) ^ (wq & 7);
            int mhIdx = wvm * MSUB + mi;
            af[mi] = *(const bf16x8*)&Alds[wq * (MH * 64) + mhIdx * 64 + u * 8];
          }
#pragma unroll
          for (int ni = 0; ni < NSUB; ++ni) {
            int row = wvn * NPW + ni * 16 + (lane & 15);
            int u = (ks * 4 + (lane >> 4)) ^ (row & 7);
            bfr[ni] = *(const bf16x8*)&Blds[row * 64 + u * 8];
          }
#pragma unroll
          for (int mi = 0; mi < MSUB; ++mi)
#pragma unroll
            for (int ni = 0; ni < NSUB; ++ni)
              acc[mi][ni] = __builtin_amdgcn_mfma_f32_16x16x32_bf16(af[mi], bfr[ni], acc[mi][ni], 0, 0, 0);
        }
      }
    }
  }

  // epilogue; C/D layout col=lane&15, row=quad*4+rr
  const int col = lane & 15;
  const int quad = lane >> 4;
#pragma unroll
  for (int ni = 0; ni < NSUB; ++ni) {
    const int co = wvn * NPW + ni * 16 + col;
    float sv = 0.f, bv = 0.f;
    if constexpr (OMODE != 2) { sv = bnS[co]; bv = bnB[co]; }
#pragma unroll
    for (int mi = 0; mi < MSUB; ++mi) {
#pragma unroll
      for (int rr = 0; rr < 4; ++rr) {
        int m = wvm * MPW + mi * 16 + quad * 4 + rr;
        int mh = m >> 4, w = m & 15;
        if constexpr (OMODE == 0) {
          float v = acc[mi][ni][rr] * sv + bv;
          v = v > 0.f ? v : SLOPE * v;
          size_t o = ((size_t)b * 78408 +
                      (size_t)((d + 1) * 1188 + (h0 + mh + 1) * 18 + (w + 1))) * CO + co;
          padOut[o] = f2bf(v);
        } else if constexpr (OMODE == 1) {
          float v = acc[mi][ni][rr] * sv + bv;
          v = v > 0.f ? v : SLOPE * v;
          size_t o = ((size_t)b * 65536 + (size_t)((d * 64 + h0 + mh) * 16 + w)) * CO + co;
          fOut[o] = v;
        } else {
          // raw f32 partial (split-K half); BN/LeakyReLU applied in reduce2
          size_t o = ((size_t)b * 65536 + (size_t)((d * 64 + h0 + mh) * 16 + w)) * CO + co;
          fOut[o] = acc[mi][ni][rr];
        }
      }
    }
  }
}

// ---------------------------------------------------------------------------
// reduce2: sum the two conv2 split-K partials, BN+LeakyReLU, write padded
// bf16 pad2.  part layout [ks][b][65536 voxels][64co] f32.  8,388,608 elems
// per half; float4 per thread -> 8192 blocks.
// ---------------------------------------------------------------------------
__global__ __launch_bounds__(256) void reduce2(const float* __restrict__ part,
                                               const float* __restrict__ s2,
                                               const float* __restrict__ be2,
                                               uint16_t* __restrict__ pad2) {
  int idx = blockIdx.x * 256 + threadIdx.x;
  int i = idx * 4;
  float4 p0 = *(const float4*)(part + i);
  float4 p1 = *(const float4*)(part + 8388608 + i);
  int co0 = i & 63;
  int voxel = i >> 6;
  int b = voxel >> 16, r = voxel & 65535;
  int d = r >> 10, hw = r & 1023, h = hw >> 4, w = hw & 15;
  float sum[4] = {p0.x + p1.x, p0.y + p1.y, p0.z + p1.z, p0.w + p1.w};
  uint16_t o[4];
#pragma unroll
  for (int j = 0; j < 4; ++j) {
    float y = sum[j] * s2[co0 + j] + be2[co0 + j];
    y = y > 0.f ? y : SLOPE * y;
    o[j] = f2bf(y);
  }
  uint16_t* dst = pad2 + ((size_t)b * 78408 +
                          (size_t)((d + 1) * 1188 + (h + 1) * 18 + (w + 1))) * 64 + co0;
  *(uint2*)dst = *(uint2*)o;
}

// ---------------------------------------------------------------------------
// gather + point MLP, all fp32. One thread per point.
// ---------------------------------------------------------------------------
__global__ __launch_bounds__(256) void gather_mlp(const float* __restrict__ x3,
                                                  const int* __restrict__ gidx,
                                                  const float* __restrict__ xyz,
                                                  const float* __restrict__ Wo1,
                                                  const float* __restrict__ so,
                                                  const float* __restrict__ beo,
                                                  const float* __restrict__ Wo2,
                                                  const float* __restrict__ bo2,
                                                  float* __restrict__ out) {
  __shared__ __align__(16) float w1[35 * 32];
  __shared__ float w2[32 * 3];
  __shared__ float sS[32], sB[32], b2s[3];
  int tid = threadIdx.x;
  for (int i = tid; i < 1120; i += 256) w1[i] = Wo1[i];
  if (tid < 96) w2[tid] = Wo2[tid];
  if (tid < 32) { sS[tid] = so[tid]; sB[tid] = beo[tid]; }
  if (tid < 3) b2s[tid] = bo2[tid];
  __syncthreads();

  int idx = blockIdx.x * 256 + tid;
  if (idx >= 200000) return;
  int b = idx >= 100000 ? 1 : 0;
  int gb = idx * 3;
  int i0 = gidx[gb], i1 = gidx[gb + 1], i2 = gidx[gb + 2];
  const float* pt = x3 + ((size_t)b * 65536 + (size_t)((i0 * 64 + i1) * 16 + i2)) * 32;

  float h[35];
#pragma unroll
  for (int q = 0; q < 8; ++q) {
    float4 v = *(const float4*)(pt + q * 4);
    h[q * 4] = v.x; h[q * 4 + 1] = v.y; h[q * 4 + 2] = v.z; h[q * 4 + 3] = v.w;
  }
  h[32] = xyz[gb]; h[33] = xyz[gb + 1]; h[34] = xyz[gb + 2];

  float a[32];
#pragma unroll
  for (int j = 0; j < 32; ++j) a[j] = 0.f;
#pragma unroll
  for (int k = 0; k < 35; ++k) {
    float hk = h[k];
    const float4* wr = (const float4*)(w1 + k * 32);
#pragma unroll
    for (int q = 0; q < 8; ++q) {
      float4 wv = wr[q];
      a[q * 4 + 0] += hk * wv.x;
      a[q * 4 + 1] += hk * wv.y;
      a[q * 4 + 2] += hk * wv.z;
      a[q * 4 + 3] += hk * wv.w;
    }
  }
  float o0 = b2s[0], o1 = b2s[1], o2 = b2s[2];
#pragma unroll
  for (int j = 0; j < 32; ++j) {
    float y = a[j] * sS[j] + sB[j];
    y = y > 0.f ? y : 0.f;
    o0 += y * w2[j * 3 + 0];
    o1 += y * w2[j * 3 + 1];
    o2 += y * w2[j * 3 + 2];
  }
  out[gb] = o0; out[gb + 1] = o1; out[gb + 2] = o2;
}

// ---------------------------------------------------------------------------
// workspace layout (bytes), lifetime-tetris'd for split-K conv2:
//   [0, 80,289,792)       pad0 (dead after conv1)
//       reused: part @0 (67,108,864, conv2 halves -> reduce2), then
//               x3 @0 (16,777,216, conv3 -> gather; part dead by then)
//   [80,289,792, 160,579,584)  pad1 (dead after conv2 halves)
//       reused: pad2 @80,289,792 (20,072,448, reduce2 -> conv3)
//   Wt1 @160,579,584 (3,538,944); Wt2 @164,118,528 (884,736);
//   Wt3 @165,003,264 (110,592); bn @165,113,856 (8 x 1024B)
// total ~165.2 MB.  Halos via halo_zero (interiors fully rewritten each
// iteration).  A-staging dummy slots may read <=1KB past a pad buffer's
// end -- always into the next allocated ws region, never past ws.
// ---------------------------------------------------------------------------
extern "C" void kernel_launch(void* const* d_in, const int* in_sizes, int n_in,
                              void* d_out, int out_size, void* d_ws, size_t ws_size,
                              hipStream_t stream) {
  (void)in_sizes; (void)n_in; (void)out_size;
  if (ws_size < 165130000) return;  // workspace too small — bail loudly (absmax will fail)

  const float* fea = (const float*)d_in[0];
  const int*   gidx = (const int*)d_in[1];
  const float* xyz = (const float*)d_in[2];
  const float* W1 = (const float*)d_in[3];
  const float* g1 = (const float*)d_in[4];
  const float* b1 = (const float*)d_in[5];
  const float* m1 = (const float*)d_in[6];
  const float* v1 = (const float*)d_in[7];
  const float* W2 = (const float*)d_in[8];
  const float* g2 = (const float*)d_in[9];
  const float* b2 = (const float*)d_in[10];
  const float* m2 = (const float*)d_in[11];
  const float* v2 = (const float*)d_in[12];
  const float* W3 = (const float*)d_in[13];
  const float* g3 = (const float*)d_in[14];
  const float* b3 = (const float*)d_in[15];
  const float* m3 = (const float*)d_in[16];
  const float* v3 = (const float*)d_in[17];
  const float* Wo1 = (const float*)d_in[18];
  const float* bo1 = (const float*)d_in[19];
  const float* go = (const float*)d_in[20];
  const float* bo = (const float*)d_in[21];
  const float* mo = (const float*)d_in[22];
  const float* vo = (const float*)d_in[23];
  const float* Wo2 = (const float*)d_in[24];
  const float* bo2 = (const float*)d_in[25];

  char* ws = (char*)d_ws;
  uint16_t* pad0 = (uint16_t*)(ws);
  uint16_t* pad1 = (uint16_t*)(ws + 80289792);
  uint16_t* Wt1 = (uint16_t*)(ws + 160579584);
  uint16_t* Wt2 = (uint16_t*)(ws + 164118528);
  uint16_t* Wt3 = (uint16_t*)(ws + 165003264);
  float* s1  = (float*)(ws + 165113856 + 0 * 1024);
  float* be1 = (float*)(ws + 165113856 + 1 * 1024);
  float* s2  = (float*)(ws + 165113856 + 2 * 1024);
  float* be2 = (float*)(ws + 165113856 + 3 * 1024);
  float* s3  = (float*)(ws + 165113856 + 4 * 1024);
  float* be3 = (float*)(ws + 165113856 + 5 * 1024);
  float* so  = (float*)(ws + 165113856 + 6 * 1024);
  float* beo = (float*)(ws + 165113856 + 7 * 1024);
  // lifetime-overlapped aliases (see layout comment)
  float*    part = (float*)(ws);                      // [2][8,388,608] f32
  uint16_t* pad2 = (uint16_t*)(ws + 80289792);        // in dead pad1
  float*    x3   = (float*)(ws);                      // after part is dead

  prep_bn<<<1, 256, 0, stream>>>(g1, b1, m1, v1, g2, b2, m2, v2, g3, b3, m3, v3,
                                 go, bo, mo, vo, bo1, s1, be1, s2, be2, s3, be3, so, beo);
  wtrans<<<6912, 256, 0, stream>>>(W1, Wt1, 256, 256);
  wtrans<<<1728, 256, 0, stream>>>(W2, Wt2, 64, 256);
  wtrans<<<216, 256, 0, stream>>>(W3, Wt3, 32, 64);
  // pad0+pad1 halos (contiguous, both C=256: 4 batch-planes)
  halo_zero<256><<<17424, 256, 0, stream>>>(pad0);
  transpose_fea<<<1024, 256, 0, stream>>>(fea, pad0);

  // conv1: EXACT round-0 config (proven 400us): CI=256,CO=256,MH=8, waves 2x2,
  // per-wave 64x128, LDS 53,248 -> 2 blocks/CU.
  conv_mfma<256, 256, 8, 2, 2, 0, 4, 2, 0>
      <<<1024, 256, 0, stream>>>(pad0, Wt1, s1, be1, pad1, nullptr);

  // conv2 split-K x2: round-0 inner loop, kc in {0,1} / {2,3}.  Raw f32
  // partials into part[ks].  LDS 45,056 -> 3 blocks/CU, 1024 blocks total
  // (12 waves/CU vs 8 unsplit).
  conv_mfma<256, 64, 16, 4, 1, 0, 2, 3, 2>
      <<<512, 256, 0, stream>>>(pad1, Wt2, nullptr, nullptr, nullptr, part);
  conv_mfma<256, 64, 16, 4, 1, 2, 2, 3, 2>
      <<<512, 256, 0, stream>>>(pad1, Wt2, nullptr, nullptr, nullptr, part + 8388608);

  // pad2 halo (pad1 dead after conv2 halves; stream-ordered)
  halo_zero<64><<<8712, 256, 0, stream>>>(pad2);
  // sum partials + BN + LeakyReLU -> padded bf16 pad2
  reduce2<<<8192, 256, 0, stream>>>(part, s2, be2, pad2);

  // conv3: round-0 config: CI=64, CO=32, MH=16, waves 4x1, per-wave 64x32
  conv_mfma<64, 32, 16, 4, 1, 0, 1, 2, 1>
      <<<512, 256, 0, stream>>>(pad2, Wt3, s3, be3, nullptr, x3);

  gather_mlp<<<782, 256, 0, stream>>>(x3, gidx, xyz, Wo1, so, beo, Wo2, bo2, (float*)d_out);
}